// Round 15
// baseline (138.595 us; speedup 1.0000x reference)
//
#include <hip/hip_runtime.h>
#include <hip/hip_bf16.h>

#define B_  2
#define T_  2048
#define C_  1024
#define H_  8
#define HD_ 128
#define M_  (B_*T_)   // 4096

typedef short  bf16x8 __attribute__((ext_vector_type(8)));
typedef float  f32x4  __attribute__((ext_vector_type(4)));
typedef unsigned short u16x8 __attribute__((ext_vector_type(8)));
typedef unsigned int   u32x4 __attribute__((ext_vector_type(4)));

typedef const __attribute__((address_space(1))) void* gas_ptr;
typedef __attribute__((address_space(3))) void*       las_ptr;

#define L2E_ 1.4426950408889634f

static __device__ __forceinline__ unsigned short f2bf(float f) {
    unsigned int u = __float_as_uint(f);
    u += 0x7fffu + ((u >> 16) & 1u);   // round-to-nearest-even
    return (unsigned short)(u >> 16);
}
static __device__ __forceinline__ unsigned int rne_u32(float f) {
    unsigned int u = __float_as_uint(f);
    return u + 0x7fffu + ((u >> 16) & 1u);   // RNE-adjusted; bf16 = bytes 2,3
}
static __device__ __forceinline__ float bf2f(unsigned short u) {
    return __uint_as_float(((unsigned int)u) << 16);
}
static __device__ __forceinline__ float exp2_fast(float x) {
#if __has_builtin(__builtin_amdgcn_exp2f)
    return __builtin_amdgcn_exp2f(x);
#else
    return exp2f(x);
#endif
}

// ---------------- fp32 -> bf16 conversion for Wv, Wo (x fused into proj) -----
__global__ __launch_bounds__(256) void k_convert_w(const float* __restrict__ Wv,
                                                   const float* __restrict__ Wo,
                                                   unsigned short* __restrict__ wvbf,
                                                   unsigned short* __restrict__ wobf) {
    int i = blockIdx.x * 256 + threadIdx.x;      // units of float4; total 524288
    const float* src; unsigned short* dst; int off;
    if (i < 262144) { src = Wv; dst = wvbf; off = i; }
    else            { src = Wo; dst = wobf; off = i - 262144; }
    float4 v = reinterpret_cast<const float4*>(src)[off];
    ushort4 o;
    o.x = f2bf(v.x); o.y = f2bf(v.y); o.z = f2bf(v.z); o.w = f2bf(v.w);
    reinterpret_cast<ushort4*>(dst)[off] = o;
}

// ---------------- q/k tiny projection + fused x->bf16 ------------------------
// qt = log2e * [q3*scale, q3.dir]; kt = [k3, k3.dir]   layout [b*H+h][T] float4
__global__ __launch_bounds__(256) void k_proj_qk(const float* __restrict__ x,
                                                 const float* __restrict__ Wq,
                                                 const float* __restrict__ Wk,
                                                 const float* __restrict__ scale_p,
                                                 float* __restrict__ qt,
                                                 float* __restrict__ kt,
                                                 unsigned short* __restrict__ xbf) {
    __shared__ __align__(16) float wl[48][260];
    __shared__ __align__(16) float xl[16][260];
    __shared__ float res[16][48];
    const int tid  = threadIdx.x;
    const int row0 = blockIdx.x << 4;
    const int r    = tid >> 4, sub = tid & 15;
    float a0 = 0.f, a1 = 0.f, a2 = 0.f;

    for (int ch = 0; ch < 4; ++ch) {
        const int k0 = ch * 256;
        #pragma unroll
        for (int i = 0; i < 12; ++i) {
            int fi = i * 256 + tid;            // 0..3071
            int wr = fi >> 6, wc = (fi & 63) * 4;
            const float* src = (wr < 24) ? (Wq + (size_t)wr * C_) : (Wk + (size_t)(wr - 24) * C_);
            *reinterpret_cast<float4*>(&wl[wr][wc]) = *reinterpret_cast<const float4*>(src + k0 + wc);
        }
        #pragma unroll
        for (int i = 0; i < 4; ++i) {
            int fi = i * 256 + tid;            // 0..1023
            int xr = fi >> 6, xc = (fi & 63) * 4;
            size_t goff = (size_t)(row0 + xr) * C_ + k0 + xc;
            float4 xv = *reinterpret_cast<const float4*>(x + goff);
            *reinterpret_cast<float4*>(&xl[xr][xc]) = xv;
            ushort4 o;
            o.x = f2bf(xv.x); o.y = f2bf(xv.y); o.z = f2bf(xv.z); o.w = f2bf(xv.w);
            *reinterpret_cast<ushort4*>(xbf + goff) = o;   // fused x conversion
        }
        __syncthreads();
        const int oc = sub * 3;
        #pragma unroll 4
        for (int k = 0; k < 256; k += 4) {
            float4 xv = *reinterpret_cast<const float4*>(&xl[r][k]);
            float4 w0 = *reinterpret_cast<const float4*>(&wl[oc + 0][k]);
            float4 w1 = *reinterpret_cast<const float4*>(&wl[oc + 1][k]);
            float4 w2 = *reinterpret_cast<const float4*>(&wl[oc + 2][k]);
            a0 += xv.x * w0.x + xv.y * w0.y + xv.z * w0.z + xv.w * w0.w;
            a1 += xv.x * w1.x + xv.y * w1.y + xv.z * w1.z + xv.w * w1.w;
            a2 += xv.x * w2.x + xv.y * w2.y + xv.z * w2.z + xv.w * w2.w;
        }
        __syncthreads();
    }
    res[r][sub * 3 + 0] = a0;
    res[r][sub * 3 + 1] = a1;
    res[r][sub * 3 + 2] = a2;
    __syncthreads();

    {   // 16 rows x 16 (isK,h) = 256 threads
        const int rr = tid >> 4, s2 = tid & 15;
        const int isK = s2 >> 3, h = s2 & 7;
        const float r3 = 0.57735026918962576f;
        float d0 = (h & 4) ? r3 : -r3;
        float d1 = (h & 2) ? r3 : -r3;
        float d2 = (h & 1) ? r3 : -r3;
        const float* v3 = &res[rr][isK * 24 + h * 3];
        float a = v3[0], b = v3[1], c = v3[2];
        float ond = a * d0 + b * d1 + c * d2;
        float sc = scale_p[0];
        float4 ov = isK ? make_float4(a, b, c, ond)
                        : make_float4(a * sc * L2E_, b * sc * L2E_, c * sc * L2E_, ond * L2E_);
        float* dst = isK ? kt : qt;
        int grow = row0 + rr;
        int b_ = grow >> 11, t_idx = grow & (T_ - 1);
        reinterpret_cast<float4*>(dst)[(size_t)(b_ * H_ + h) * T_ + t_idx] = ov;
    }
}

// ---------------- bf16 MFMA GEMM, 128x64 tile, BK=64 (single-buffer) ---------
// MODE 0: fp32 out [M][N].  MODE 2: bf16 out transposed into vt[(b*C+col)][t].
template <int MODE>
__global__ __launch_bounds__(256) void k_gemm128x64(const unsigned short* __restrict__ A,
                                                    const unsigned short* __restrict__ Bw,
                                                    void* __restrict__ Cout,
                                                    int Mdim, int Ndim, int Kdim) {
    __shared__ __align__(16) unsigned short lds_a[8][128][8];  // [kq][row][8]  16KB
    __shared__ __align__(16) unsigned short lds_b[8][64][8];   //               8KB
    const int tid = threadIdx.x;
    const int nbn = Ndim >> 6;
    const int bm = (blockIdx.x / nbn) << 7;
    const int bn = (blockIdx.x % nbn) << 6;
    const int w = tid >> 6, l = tid & 63;
    const int wm = (w >> 1) << 6, wn = (w & 1) << 5;
    const int lh = l & 15, lq = l >> 4;

    f32x4 acc[4][2];
    #pragma unroll
    for (int i = 0; i < 4; ++i)
        #pragma unroll
        for (int j = 0; j < 2; ++j)
            acc[i][j] = (f32x4){0.f, 0.f, 0.f, 0.f};

    for (int k0 = 0; k0 < Kdim; k0 += 64) {
        #pragma unroll
        for (int p = 0; p < 4; ++p) {
            int flat = p * 256 + tid;          // 0..1023 ; kq = flat>>7, row = flat&127
            int kq = flat >> 7, row = flat & 127;
            __builtin_amdgcn_global_load_lds((gas_ptr)(A + (size_t)(bm + row) * Kdim + k0 + kq * 8),
                (las_ptr)(&lds_a[0][0][0] + (size_t)flat * 8), 16, 0, 0);
        }
        #pragma unroll
        for (int p = 0; p < 2; ++p) {
            int flat = p * 256 + tid;          // 0..511 ; kq = flat>>6, row = flat&63
            int kq = flat >> 6, row = flat & 63;
            __builtin_amdgcn_global_load_lds((gas_ptr)(Bw + (size_t)(bn + row) * Kdim + k0 + kq * 8),
                (las_ptr)(&lds_b[0][0][0] + (size_t)flat * 8), 16, 0, 0);
        }
        __syncthreads();

        #pragma unroll
        for (int kk = 0; kk < 2; ++kk) {
            bf16x8 af[4], bfr[2];
            #pragma unroll
            for (int f = 0; f < 4; ++f)
                af[f] = *reinterpret_cast<const bf16x8*>(&lds_a[lq + 4 * kk][wm + f * 16 + lh][0]);
            #pragma unroll
            for (int f = 0; f < 2; ++f)
                bfr[f] = *reinterpret_cast<const bf16x8*>(&lds_b[lq + 4 * kk][wn + f * 16 + lh][0]);
            #pragma unroll
            for (int i = 0; i < 4; ++i)
                #pragma unroll
                for (int j = 0; j < 2; ++j)
                    acc[i][j] = __builtin_amdgcn_mfma_f32_16x16x32_bf16(af[i], bfr[j], acc[i][j], 0, 0, 0);
        }
        __syncthreads();
    }

    if constexpr (MODE == 0) {
        float* Cf = (float*)Cout;
        #pragma unroll
        for (int i = 0; i < 4; ++i) {
            int rbase = bm + wm + i * 16 + lq * 4;
            #pragma unroll
            for (int j = 0; j < 2; ++j) {
                int cidx = bn + wn + j * 16 + lh;
                #pragma unroll
                for (int r = 0; r < 4; ++r)
                    Cf[(size_t)(rbase + r) * Ndim + cidx] = acc[i][j][r];
            }
        }
    } else {
        __shared__ unsigned short ldsT[128][72];
        #pragma unroll
        for (int i = 0; i < 4; ++i)
            #pragma unroll
            for (int j = 0; j < 2; ++j)
                #pragma unroll
                for (int r = 0; r < 4; ++r)
                    ldsT[wm + i * 16 + lq * 4 + r][wn + j * 16 + lh] = f2bf(acc[i][j][r]);
        __syncthreads();
        unsigned short* vt_out = (unsigned short*)Cout;
        int c = tid & 63, part = tid >> 6;
        int b = bm >> 11, t0 = bm & (T_ - 1);
        unsigned short* dst = vt_out + ((size_t)b * C_ + bn + c) * T_ + t0 + part * 32;
        #pragma unroll
        for (int jj = 0; jj < 4; ++jj) {
            u16x8 v;
            #pragma unroll
            for (int k = 0; k < 8; ++k) v[k] = ldsT[part * 32 + jj * 8 + k][c];
            *reinterpret_cast<u16x8*>(dst + jj * 8) = v;
        }
    }
}

// ---------------- flash attention, paired q-blocks {p, 31-p}, KVBLK=64 -------
// grid: 16 pairs (heavy first) x nsp x 16 bh = 1024 blocks; 4 waves.
// Block owns 128 q-rows: 16/wave from LOWER qb=p and 16/wave from UPPER
// qb=31-p (rows q0+4*lh+w). Lower's K/V tiles are a SUBSET of upper's, so
// each staged tile feeds BOTH row-groups (2x MFMA per stage/barrier, 2x ILP).
// Lower group is skipped block-uniformly once st > p; its empty splits write
// (m=-1e30, l=0) partials which the online combine absorbs.
__global__ __launch_bounds__(256) void k_attn_pair64(
        const float4* __restrict__ qt, const float4* __restrict__ kt,
        const unsigned short* __restrict__ vt,
        unsigned short* __restrict__ mpart,       // [nsp][16][2048][128] bf16 (unnormalized)
        float2* __restrict__ mlbuf,               // [nsp][16][2048] (m, lsum)
        int nsp, int lg2nsp) {
    __shared__ __align__(16) unsigned short lv[2][8192];   // 2 x 16KB V-tiles [128d][64s]
    __shared__ __align__(16) float4 lk[2][64];             // 2 x 1KB K-tiles
    const int tid = threadIdx.x;
    const int w = tid >> 6, l = tid & 63;
    const int lh = l & 15, lg = l >> 4;
    const int bid = blockIdx.x;
    const int pr  = bid >> (4 + lg2nsp);          // 0..15, heaviest pair first
    const int sp  = (bid >> 4) & (nsp - 1);
    const int bh  = bid & 15;
    const int qa  = pr;                           // lower q-block
    const int qbg = 31 - pr;                      // upper q-block
    const int q0a = qa << 6, q0b = qbg << 6;
    const int qrowA = q0a + 4 * lh + w;
    const int qrowB = q0b + 4 * lh + w;
    const int nt = qbg + 1;                       // 64-col tiles (upper's range)

    const float4* qtb = qt + (size_t)bh * T_;
    const float4* ktb = kt + (size_t)bh * T_;
    const unsigned short* vtb = vt + (size_t)bh * HD_ * T_;

    // staging sources: flat slot f (16B) -> (kt2 = f>>9, n = (f>>6)&7,
    // lg2 = (f>>4)&3, lh2 = f&15); src = vtb[(n*16+lh2)*T + kt2*32 + lg2*8 + s0]
    const unsigned short* vsrc[4];
    #pragma unroll
    for (int i = 0; i < 4; ++i) {
        int f = i * 256 + tid;
        vsrc[i] = vtb + (size_t)((((f >> 6) & 7) * 16) + (f & 15)) * T_
                      + ((f >> 9) << 5) + ((f >> 4) & 3) * 8;
    }

#define STAGE(ST, BUF) do {                                                    \
    int s0_ = (ST) << 6;                                                       \
    __builtin_amdgcn_global_load_lds((gas_ptr)(vsrc[0] + s0_),                 \
        (las_ptr)(&lv[BUF][0] + (size_t)(0 * 256 + tid) * 8), 16, 0, 0);       \
    __builtin_amdgcn_global_load_lds((gas_ptr)(vsrc[1] + s0_),                 \
        (las_ptr)(&lv[BUF][0] + (size_t)(1 * 256 + tid) * 8), 16, 0, 0);       \
    __builtin_amdgcn_global_load_lds((gas_ptr)(vsrc[2] + s0_),                 \
        (las_ptr)(&lv[BUF][0] + (size_t)(2 * 256 + tid) * 8), 16, 0, 0);       \
    __builtin_amdgcn_global_load_lds((gas_ptr)(vsrc[3] + s0_),                 \
        (las_ptr)(&lv[BUF][0] + (size_t)(3 * 256 + tid) * 8), 16, 0, 0);       \
    __builtin_amdgcn_global_load_lds((gas_ptr)(ktb + s0_ + l),                 \
        (las_ptr)(&lk[BUF][0]), 16, 0, 0);                                     \
} while (0)

// One row-group's tile body: scores -> online softmax -> pack -> 16 MFMA.
// EDGE (st == group's qb) applies the pre-exp causal mask only; -1e30 scores
// flush to exactly 0 through exp2 even with the deferred (stale) max.
#define TILE_GROUP(Q4, MM, LS, ACC, EDGE, QROW) do {                           \
    float p[16];                                                               \
    if (!(EDGE)) {                                                             \
        _Pragma("unroll")                                                      \
        for (int jj = 0; jj < 8; ++jj) {                                       \
            float4 k4 = lk[buf][lg * 8 + jj];                                  \
            p[jj] = fmaf((Q4).x, k4.x, fmaf((Q4).y, k4.y,                      \
                     fmaf((Q4).z, k4.z, (Q4).w * k4.w)));                      \
        }                                                                      \
        _Pragma("unroll")                                                      \
        for (int jj = 0; jj < 8; ++jj) {                                       \
            float4 k4 = lk[buf][32 + lg * 8 + jj];                             \
            p[8 + jj] = fmaf((Q4).x, k4.x, fmaf((Q4).y, k4.y,                  \
                         fmaf((Q4).z, k4.z, (Q4).w * k4.w)));                  \
        }                                                                      \
    } else {                                                                   \
        _Pragma("unroll")                                                      \
        for (int jj = 0; jj < 8; ++jj) {                                       \
            float4 k4 = lk[buf][lg * 8 + jj];                                  \
            float sc = fmaf((Q4).x, k4.x, fmaf((Q4).y, k4.y,                   \
                        fmaf((Q4).z, k4.z, (Q4).w * k4.w)));                   \
            p[jj] = (c0 + jj > (QROW)) ? -1e30f : sc;                          \
        }                                                                      \
        _Pragma("unroll")                                                      \
        for (int jj = 0; jj < 8; ++jj) {                                       \
            float4 k4 = lk[buf][32 + lg * 8 + jj];                             \
            float sc = fmaf((Q4).x, k4.x, fmaf((Q4).y, k4.y,                   \
                        fmaf((Q4).z, k4.z, (Q4).w * k4.w)));                   \
            p[8 + jj] = (c1 + jj > (QROW)) ? -1e30f : sc;                      \
        }                                                                      \
    }                                                                          \
    float ma = fmaxf(fmaxf(p[0], p[1]), p[2]);                                 \
    float mb = fmaxf(fmaxf(p[3], p[4]), p[5]);                                 \
    float mc = fmaxf(fmaxf(p[6], p[7]), p[8]);                                 \
    float md = fmaxf(fmaxf(p[9], p[10]), p[11]);                               \
    float me = fmaxf(fmaxf(p[12], p[13]), p[14]);                              \
    float mt = fmaxf(fmaxf(fmaxf(ma, mb), fmaxf(mc, md)), fmaxf(me, p[15]));   \
    mt = fmaxf(mt, __shfl_xor(mt, 16));                                        \
    mt = fmaxf(mt, __shfl_xor(mt, 32));                                        \
    if (__any(mt > (MM) + 8.f)) {                                              \
        float mnew = fmaxf((MM), mt);                                          \
        float corr = exp2_fast((MM) - mnew);                                   \
        (MM) = mnew;                                                           \
        (LS) *= corr;                                                          \
        float cc0 = __shfl(corr, 4 * lg + 0);                                  \
        float cc1 = __shfl(corr, 4 * lg + 1);                                  \
        float cc2 = __shfl(corr, 4 * lg + 2);                                  \
        float cc3 = __shfl(corr, 4 * lg + 3);                                  \
        _Pragma("unroll")                                                      \
        for (int n = 0; n < 8; ++n) {                                          \
            (ACC)[n][0] *= cc0; (ACC)[n][1] *= cc1;                            \
            (ACC)[n][2] *= cc2; (ACC)[n][3] *= cc3;                            \
        }                                                                      \
    }                                                                          \
    _Pragma("unroll")                                                          \
    for (int jj = 0; jj < 16; ++jj)                                            \
        p[jj] = exp2_fast(p[jj] - (MM));                                       \
    float sa = (p[0] + p[1] + p[2]) + (p[3] + p[4] + p[5]);                    \
    float sb = (p[6] + p[7] + p[8]) + (p[9] + p[10] + p[11]);                  \
    float ps = sa + sb + ((p[12] + p[13] + p[14]) + p[15]);                    \
    ps += __shfl_xor(ps, 16);                                                  \
    ps += __shfl_xor(ps, 32);                                                  \
    (LS) += ps;                                                                \
    u32x4 w0_, w1_;                                                            \
    _Pragma("unroll")                                                          \
    for (int i = 0; i < 4; ++i) {                                              \
        w0_[i] = __builtin_amdgcn_perm(rne_u32(p[2 * i + 1]),                  \
                                       rne_u32(p[2 * i]), 0x07060302u);        \
        w1_[i] = __builtin_amdgcn_perm(rne_u32(p[8 + 2 * i + 1]),              \
                                       rne_u32(p[8 + 2 * i]), 0x07060302u);    \
    }                                                                          \
    bf16x8 pa0 = __builtin_bit_cast(bf16x8, w0_);                              \
    bf16x8 pa1 = __builtin_bit_cast(bf16x8, w1_);                              \
    _Pragma("unroll")                                                          \
    for (int n = 0; n < 8; ++n) {                                              \
        bf16x8 vf = *reinterpret_cast<const bf16x8*>(                          \
            &lv[buf][(size_t)(n * 64 + lg * 16 + lh) * 8]);                    \
        (ACC)[n] = __builtin_amdgcn_mfma_f32_16x16x32_bf16(pa0, vf, (ACC)[n], 0, 0, 0); \
    }                                                                          \
    _Pragma("unroll")                                                          \
    for (int n = 0; n < 8; ++n) {                                              \
        bf16x8 vf = *reinterpret_cast<const bf16x8*>(                          \
            &lv[buf][(size_t)(512 + n * 64 + lg * 16 + lh) * 8]);              \
        (ACC)[n] = __builtin_amdgcn_mfma_f32_16x16x32_bf16(pa1, vf, (ACC)[n], 0, 0, 0); \
    }                                                                          \
} while (0)

    const float4 q4a = qtb[qrowA];
    const float4 q4b = qtb[qrowB];
    f32x4 accA[8], accB[8];
    #pragma unroll
    for (int n = 0; n < 8; ++n) {
        accA[n] = (f32x4){0.f, 0.f, 0.f, 0.f};
        accB[n] = (f32x4){0.f, 0.f, 0.f, 0.f};
    }
    float mA = -1e30f, lsA = 0.f;
    float mB = -1e30f, lsB = 0.f;

    STAGE(sp, 0);                                 // sp < nsp <= 8 <= nt always
    __syncthreads();                              // drains vmcnt before barrier

    int buf = 0;
    for (int st = sp; st < nt; st += nsp) {
        if (st + nsp < nt) STAGE(st + nsp, buf ^ 1);

        const int s0 = st << 6;
        const int c0 = s0 + lg * 8;               // cols of p[0..8)
        const int c1 = s0 + 32 + lg * 8;          // cols of p[8..16)

        // upper group: always active; mask only at its edge tile
        TILE_GROUP(q4b, mB, lsB, accB, st == qbg, qrowB);
        // lower group: active while st <= qa (block-uniform)
        if (st <= qa)
            TILE_GROUP(q4a, mA, lsA, accA, st == qa, qrowA);

        __syncthreads();                          // buf released; buf^1 staged & drained
        buf ^= 1;
    }
#undef TILE_GROUP
#undef STAGE

    unsigned short* mp = mpart + (size_t)(sp * 16 + bh) * T_ * HD_;
    #pragma unroll
    for (int n = 0; n < 8; ++n) {
        #pragma unroll
        for (int r = 0; r < 4; ++r) {
            int rowB = q0b + 16 * lg + 4 * r + w; // D-frag row = lg*4+r -> q-row
            mp[(size_t)rowB * HD_ + n * 16 + lh] = f2bf(accB[n][r]);
            int rowA = q0a + 16 * lg + 4 * r + w;
            mp[(size_t)rowA * HD_ + n * 16 + lh] = f2bf(accA[n][r]);
        }
    }
    if (lg == 0) {
        mlbuf[(size_t)(sp * 16 + bh) * T_ + qrowB] = make_float2(mB, lsB);
        mlbuf[(size_t)(sp * 16 + bh) * T_ + qrowA] = make_float2(mA, lsA);
    }
}

// ---------------- combine nsp s-split partials -> attnbf (bf16), online ------
__global__ __launch_bounds__(256) void k_combine(const unsigned short* __restrict__ mpart,
                                                 const float2* __restrict__ mlbuf,
                                                 unsigned short* __restrict__ attnbf,
                                                 int nsp) {
    int idx = blockIdx.x * 256 + threadIdx.x;   // [16][2048][32 d-quads]
    int bh = idx >> 16;
    int rem = idx & 65535;
    int t = rem >> 5, d0 = (rem & 31) * 4;
    float mg = -1e30f, den = 0.f;
    float ax = 0.f, ay = 0.f, az = 0.f, aw = 0.f;
    for (int s = 0; s < nsp; ++s) {
        float2 ml = mlbuf[(size_t)(s * 16 + bh) * T_ + t];
        ushort4 a = *reinterpret_cast<const ushort4*>(
            mpart + ((size_t)(s * 16 + bh) * T_ + t) * HD_ + d0);
        float mn = fmaxf(mg, ml.x);
        float cOld = exp2_fast(mg - mn);
        float cNew = exp2_fast(ml.x - mn);
        den = den * cOld + ml.y * cNew;
        ax = ax * cOld + bf2f(a.x) * cNew;
        ay = ay * cOld + bf2f(a.y) * cNew;
        az = az * cOld + bf2f(a.z) * cNew;
        aw = aw * cOld + bf2f(a.w) * cNew;
        mg = mn;
    }
    float inv = 1.f / den;
    int b = bh >> 3, h = bh & 7;
    ushort4 o;
    o.x = f2bf(ax * inv); o.y = f2bf(ay * inv);
    o.z = f2bf(az * inv); o.w = f2bf(aw * inv);
    *reinterpret_cast<ushort4*>(attnbf + ((size_t)(b * T_ + t) * C_ + h * HD_ + d0)) = o;
}

extern "C" void kernel_launch(void* const* d_in, const int* in_sizes, int n_in,
                              void* d_out, int out_size, void* d_ws, size_t ws_size,
                              hipStream_t stream) {
    const float* x     = (const float*)d_in[0];
    const float* Wq    = (const float*)d_in[1];
    const float* Wk    = (const float*)d_in[2];
    const float* Wv    = (const float*)d_in[3];
    const float* Wo    = (const float*)d_in[4];
    const float* scale = (const float*)d_in[5];
    float* out = (float*)d_out;

    // nsp=4 layout needs 46,137,344 B; fall back to nsp=2 (28,835,840 B)
    // if d_ws is smaller. Deterministic per process.
    const int nsp    = (ws_size >= 46137344) ? 4 : 2;
    const int lg2nsp = (nsp == 4) ? 2 : 1;

    char* ws = (char*)d_ws;
    // Lifetime-based layout (offsets scale with nsp):
    //   [0, nsp*8M)  mpart (attn->combine)  ALIASES: xbf [0,8M), wvbf [8M,10M)
    //   then qt (512K), kt (512K), vt (8M, ALIAS attnbf), wobf (2M), mlbuf (nsp*256K)
    size_t o = (size_t)nsp * 8388608;
    unsigned short* mpart  = (unsigned short*)(ws);
    unsigned short* xbf    = (unsigned short*)(ws);
    unsigned short* wvbf   = (unsigned short*)(ws + 8388608);
    float*          qt     = (float*)(ws + o);
    float*          kt     = (float*)(ws + o + 524288);
    unsigned short* vt     = (unsigned short*)(ws + o + 1048576);
    unsigned short* attnbf = (unsigned short*)(ws + o + 1048576);
    unsigned short* wobf   = (unsigned short*)(ws + o + 9437184);
    float2*         mlbuf  = (float2*)(ws + o + 11534336);

    k_convert_w<<<2048, 256, 0, stream>>>(Wv, Wo, wvbf, wobf);

    k_proj_qk<<<M_ / 16, 256, 0, stream>>>(x, Wq, Wk, scale, qt, kt, xbf);

    k_gemm128x64<2><<<(M_ / 128) * (C_ / 64), 256, 0, stream>>>(xbf, wvbf, (void*)vt, M_, C_, C_);

    k_attn_pair64<<<16 * nsp * 16, 256, 0, stream>>>(
        reinterpret_cast<const float4*>(qt), reinterpret_cast<const float4*>(kt), vt,
        mpart, mlbuf, nsp, lg2nsp);

    k_combine<<<4096, 256, 0, stream>>>(mpart, mlbuf, attnbf, nsp);

    k_gemm128x64<0><<<(M_ / 128) * (C_ / 64), 256, 0, stream>>>(attnbf, wobf, (void*)out, M_, C_, C_);
}

// Round 16
// 129.283 us; speedup vs baseline: 1.0720x; 1.0720x over previous
//
#include <hip/hip_runtime.h>
#include <hip/hip_bf16.h>

#define B_  2
#define T_  2048
#define C_  1024
#define H_  8
#define HD_ 128
#define M_  (B_*T_)   // 4096

typedef short  bf16x8 __attribute__((ext_vector_type(8)));
typedef float  f32x4  __attribute__((ext_vector_type(4)));
typedef unsigned short u16x8 __attribute__((ext_vector_type(8)));
typedef unsigned int   u32x4 __attribute__((ext_vector_type(4)));

typedef const __attribute__((address_space(1))) void* gas_ptr;
typedef __attribute__((address_space(3))) void*       las_ptr;

#define L2E_ 1.4426950408889634f

static __device__ __forceinline__ unsigned short f2bf(float f) {
    unsigned int u = __float_as_uint(f);
    u += 0x7fffu + ((u >> 16) & 1u);   // round-to-nearest-even
    return (unsigned short)(u >> 16);
}
static __device__ __forceinline__ unsigned int rne_u32(float f) {
    unsigned int u = __float_as_uint(f);
    return u + 0x7fffu + ((u >> 16) & 1u);   // RNE-adjusted; bf16 = bytes 2,3
}
static __device__ __forceinline__ float bf2f(unsigned short u) {
    return __uint_as_float(((unsigned int)u) << 16);
}
static __device__ __forceinline__ float exp2_fast(float x) {
#if __has_builtin(__builtin_amdgcn_exp2f)
    return __builtin_amdgcn_exp2f(x);
#else
    return exp2f(x);
#endif
}

// ---------------- fp32 -> bf16 conversion for Wv, Wo (x fused into proj) -----
__global__ __launch_bounds__(256) void k_convert_w(const float* __restrict__ Wv,
                                                   const float* __restrict__ Wo,
                                                   unsigned short* __restrict__ wvbf,
                                                   unsigned short* __restrict__ wobf) {
    int i = blockIdx.x * 256 + threadIdx.x;      // units of float4; total 524288
    const float* src; unsigned short* dst; int off;
    if (i < 262144) { src = Wv; dst = wvbf; off = i; }
    else            { src = Wo; dst = wobf; off = i - 262144; }
    float4 v = reinterpret_cast<const float4*>(src)[off];
    ushort4 o;
    o.x = f2bf(v.x); o.y = f2bf(v.y); o.z = f2bf(v.z); o.w = f2bf(v.w);
    reinterpret_cast<ushort4*>(dst)[off] = o;
}

// ---------------- q/k tiny projection + fused x->bf16 ------------------------
// qt = log2e * [q3*scale, q3.dir]; kt = [k3, k3.dir]   layout [b*H+h][T] float4
__global__ __launch_bounds__(256) void k_proj_qk(const float* __restrict__ x,
                                                 const float* __restrict__ Wq,
                                                 const float* __restrict__ Wk,
                                                 const float* __restrict__ scale_p,
                                                 float* __restrict__ qt,
                                                 float* __restrict__ kt,
                                                 unsigned short* __restrict__ xbf) {
    __shared__ __align__(16) float wl[48][260];
    __shared__ __align__(16) float xl[16][260];
    __shared__ float res[16][48];
    const int tid  = threadIdx.x;
    const int row0 = blockIdx.x << 4;
    const int r    = tid >> 4, sub = tid & 15;
    float a0 = 0.f, a1 = 0.f, a2 = 0.f;

    for (int ch = 0; ch < 4; ++ch) {
        const int k0 = ch * 256;
        #pragma unroll
        for (int i = 0; i < 12; ++i) {
            int fi = i * 256 + tid;            // 0..3071
            int wr = fi >> 6, wc = (fi & 63) * 4;
            const float* src = (wr < 24) ? (Wq + (size_t)wr * C_) : (Wk + (size_t)(wr - 24) * C_);
            *reinterpret_cast<float4*>(&wl[wr][wc]) = *reinterpret_cast<const float4*>(src + k0 + wc);
        }
        #pragma unroll
        for (int i = 0; i < 4; ++i) {
            int fi = i * 256 + tid;            // 0..1023
            int xr = fi >> 6, xc = (fi & 63) * 4;
            size_t goff = (size_t)(row0 + xr) * C_ + k0 + xc;
            float4 xv = *reinterpret_cast<const float4*>(x + goff);
            *reinterpret_cast<float4*>(&xl[xr][xc]) = xv;
            ushort4 o;
            o.x = f2bf(xv.x); o.y = f2bf(xv.y); o.z = f2bf(xv.z); o.w = f2bf(xv.w);
            *reinterpret_cast<ushort4*>(xbf + goff) = o;   // fused x conversion
        }
        __syncthreads();
        const int oc = sub * 3;
        #pragma unroll 4
        for (int k = 0; k < 256; k += 4) {
            float4 xv = *reinterpret_cast<const float4*>(&xl[r][k]);
            float4 w0 = *reinterpret_cast<const float4*>(&wl[oc + 0][k]);
            float4 w1 = *reinterpret_cast<const float4*>(&wl[oc + 1][k]);
            float4 w2 = *reinterpret_cast<const float4*>(&wl[oc + 2][k]);
            a0 += xv.x * w0.x + xv.y * w0.y + xv.z * w0.z + xv.w * w0.w;
            a1 += xv.x * w1.x + xv.y * w1.y + xv.z * w1.z + xv.w * w1.w;
            a2 += xv.x * w2.x + xv.y * w2.y + xv.z * w2.z + xv.w * w2.w;
        }
        __syncthreads();
    }
    res[r][sub * 3 + 0] = a0;
    res[r][sub * 3 + 1] = a1;
    res[r][sub * 3 + 2] = a2;
    __syncthreads();

    {   // 16 rows x 16 (isK,h) = 256 threads
        const int rr = tid >> 4, s2 = tid & 15;
        const int isK = s2 >> 3, h = s2 & 7;
        const float r3 = 0.57735026918962576f;
        float d0 = (h & 4) ? r3 : -r3;
        float d1 = (h & 2) ? r3 : -r3;
        float d2 = (h & 1) ? r3 : -r3;
        const float* v3 = &res[rr][isK * 24 + h * 3];
        float a = v3[0], b = v3[1], c = v3[2];
        float ond = a * d0 + b * d1 + c * d2;
        float sc = scale_p[0];
        float4 ov = isK ? make_float4(a, b, c, ond)
                        : make_float4(a * sc * L2E_, b * sc * L2E_, c * sc * L2E_, ond * L2E_);
        float* dst = isK ? kt : qt;
        int grow = row0 + rr;
        int b_ = grow >> 11, t_idx = grow & (T_ - 1);
        reinterpret_cast<float4*>(dst)[(size_t)(b_ * H_ + h) * T_ + t_idx] = ov;
    }
}

// ---------------- bf16 MFMA GEMM, 128x64 tile, BK=64 (single-buffer) ---------
// Bijective XCD swizzle (nwg % 8 == 0): each XCD gets a CONTIGUOUS run of
// nwg/8 blocks -> 4 A-panels (1MB) + full B (2MB) fit its 4MB L2 (T1/m204).
// MODE 0: fp32 out [M][N].  MODE 2: bf16 out transposed into vt[(b*C+col)][t].
template <int MODE>
__global__ __launch_bounds__(256) void k_gemm128x64(const unsigned short* __restrict__ A,
                                                    const unsigned short* __restrict__ Bw,
                                                    void* __restrict__ Cout,
                                                    int Mdim, int Ndim, int Kdim) {
    __shared__ __align__(16) unsigned short lds_a[8][128][8];  // [kq][row][8]  16KB
    __shared__ __align__(16) unsigned short lds_b[8][64][8];   //               8KB
    const int tid = threadIdx.x;
    const int nbn = Ndim >> 6;
    const int cpx = (int)gridDim.x >> 3;                 // blocks per XCD
    const int bidx = (blockIdx.x & 7) * cpx + (blockIdx.x >> 3);
    const int bm = (bidx / nbn) << 7;
    const int bn = (bidx % nbn) << 6;
    const int w = tid >> 6, l = tid & 63;
    const int wm = (w >> 1) << 6, wn = (w & 1) << 5;
    const int lh = l & 15, lq = l >> 4;

    f32x4 acc[4][2];
    #pragma unroll
    for (int i = 0; i < 4; ++i)
        #pragma unroll
        for (int j = 0; j < 2; ++j)
            acc[i][j] = (f32x4){0.f, 0.f, 0.f, 0.f};

    for (int k0 = 0; k0 < Kdim; k0 += 64) {
        #pragma unroll
        for (int p = 0; p < 4; ++p) {
            int flat = p * 256 + tid;          // 0..1023 ; kq = flat>>7, row = flat&127
            int kq = flat >> 7, row = flat & 127;
            __builtin_amdgcn_global_load_lds((gas_ptr)(A + (size_t)(bm + row) * Kdim + k0 + kq * 8),
                (las_ptr)(&lds_a[0][0][0] + (size_t)flat * 8), 16, 0, 0);
        }
        #pragma unroll
        for (int p = 0; p < 2; ++p) {
            int flat = p * 256 + tid;          // 0..511 ; kq = flat>>6, row = flat&63
            int kq = flat >> 6, row = flat & 63;
            __builtin_amdgcn_global_load_lds((gas_ptr)(Bw + (size_t)(bn + row) * Kdim + k0 + kq * 8),
                (las_ptr)(&lds_b[0][0][0] + (size_t)flat * 8), 16, 0, 0);
        }
        __syncthreads();

        #pragma unroll
        for (int kk = 0; kk < 2; ++kk) {
            bf16x8 af[4], bfr[2];
            #pragma unroll
            for (int f = 0; f < 4; ++f)
                af[f] = *reinterpret_cast<const bf16x8*>(&lds_a[lq + 4 * kk][wm + f * 16 + lh][0]);
            #pragma unroll
            for (int f = 0; f < 2; ++f)
                bfr[f] = *reinterpret_cast<const bf16x8*>(&lds_b[lq + 4 * kk][wn + f * 16 + lh][0]);
            #pragma unroll
            for (int i = 0; i < 4; ++i)
                #pragma unroll
                for (int j = 0; j < 2; ++j)
                    acc[i][j] = __builtin_amdgcn_mfma_f32_16x16x32_bf16(af[i], bfr[j], acc[i][j], 0, 0, 0);
        }
        __syncthreads();
    }

    if constexpr (MODE == 0) {
        float* Cf = (float*)Cout;
        #pragma unroll
        for (int i = 0; i < 4; ++i) {
            int rbase = bm + wm + i * 16 + lq * 4;
            #pragma unroll
            for (int j = 0; j < 2; ++j) {
                int cidx = bn + wn + j * 16 + lh;
                #pragma unroll
                for (int r = 0; r < 4; ++r)
                    Cf[(size_t)(rbase + r) * Ndim + cidx] = acc[i][j][r];
            }
        }
    } else {
        __shared__ unsigned short ldsT[128][72];
        #pragma unroll
        for (int i = 0; i < 4; ++i)
            #pragma unroll
            for (int j = 0; j < 2; ++j)
                #pragma unroll
                for (int r = 0; r < 4; ++r)
                    ldsT[wm + i * 16 + lq * 4 + r][wn + j * 16 + lh] = f2bf(acc[i][j][r]);
        __syncthreads();
        unsigned short* vt_out = (unsigned short*)Cout;
        int c = tid & 63, part = tid >> 6;
        int b = bm >> 11, t0 = bm & (T_ - 1);
        unsigned short* dst = vt_out + ((size_t)b * C_ + bn + c) * T_ + t0 + part * 32;
        #pragma unroll
        for (int jj = 0; jj < 4; ++jj) {
            u16x8 v;
            #pragma unroll
            for (int k = 0; k < 8; ++k) v[k] = ldsT[part * 32 + jj * 8 + k][c];
            *reinterpret_cast<u16x8*>(dst + jj * 8) = v;
        }
    }
}

// ---------------- flash attention, KVBLK=64, s-split-nsp, LDS K+V, MFMA PV ---
// grid: 32 qb (heavy first, LPT) x nsp x 16 bh = 2048 blocks.
// Block = 64 q-rows (row = q0 + 4*lh + w), nt = qb+1 uniform 64-col tiles.
// Interior tiles (st < qb) are provably unmasked; only st == qb masks (pre-exp
// only: -1e30 scores flush to exactly 0 through exp2 even with deferred max).
__global__ __launch_bounds__(256) void k_attn64(
        const float4* __restrict__ qt, const float4* __restrict__ kt,
        const unsigned short* __restrict__ vt,
        unsigned short* __restrict__ mpart,       // [nsp][16][2048][128] bf16 (unnormalized)
        float2* __restrict__ mlbuf,               // [nsp][16][2048] (m, lsum)
        int nsp, int lg2nsp) {
    __shared__ __align__(16) unsigned short lv[2][8192];   // 2 x 16KB V-tiles [128d][64s]
    __shared__ __align__(16) float4 lk[2][64];             // 2 x 1KB K-tiles
    const int tid = threadIdx.x;
    const int w = tid >> 6, l = tid & 63;
    const int lh = l & 15, lg = l >> 4;
    const int bid = blockIdx.x;
    const int qb = 31 - (bid >> (4 + lg2nsp));    // heavy q-blocks first (LPT)
    const int sp = (bid >> 4) & (nsp - 1);
    const int bh = bid & 15;
    const int q0 = qb << 6;
    const int qrow = q0 + 4 * lh + w;             // this lane's P-row (A-frag row)
    const int nt = qb + 1;                        // 64-col tiles, uniform per block

    const float4* qtb = qt + (size_t)bh * T_;
    const float4* ktb = kt + (size_t)bh * T_;
    const unsigned short* vtb = vt + (size_t)bh * HD_ * T_;

    // staging sources: flat slot f (16B) -> (kt2 = f>>9, n = (f>>6)&7,
    // lg2 = (f>>4)&3, lh2 = f&15); src = vtb[(n*16+lh2)*T + kt2*32 + lg2*8 + s0]
    const unsigned short* vsrc[4];
    #pragma unroll
    for (int i = 0; i < 4; ++i) {
        int f = i * 256 + tid;
        vsrc[i] = vtb + (size_t)((((f >> 6) & 7) * 16) + (f & 15)) * T_
                      + ((f >> 9) << 5) + ((f >> 4) & 3) * 8;
    }

#define STAGE(ST, BUF) do {                                                    \
    int s0_ = (ST) << 6;                                                       \
    __builtin_amdgcn_global_load_lds((gas_ptr)(vsrc[0] + s0_),                 \
        (las_ptr)(&lv[BUF][0] + (size_t)(0 * 256 + tid) * 8), 16, 0, 0);       \
    __builtin_amdgcn_global_load_lds((gas_ptr)(vsrc[1] + s0_),                 \
        (las_ptr)(&lv[BUF][0] + (size_t)(1 * 256 + tid) * 8), 16, 0, 0);       \
    __builtin_amdgcn_global_load_lds((gas_ptr)(vsrc[2] + s0_),                 \
        (las_ptr)(&lv[BUF][0] + (size_t)(2 * 256 + tid) * 8), 16, 0, 0);       \
    __builtin_amdgcn_global_load_lds((gas_ptr)(vsrc[3] + s0_),                 \
        (las_ptr)(&lv[BUF][0] + (size_t)(3 * 256 + tid) * 8), 16, 0, 0);       \
    __builtin_amdgcn_global_load_lds((gas_ptr)(ktb + s0_ + l),                 \
        (las_ptr)(&lk[BUF][0]), 16, 0, 0);                                     \
} while (0)

    const float4 q4 = qtb[qrow];
    f32x4 acc[8];
    #pragma unroll
    for (int n = 0; n < 8; ++n) acc[n] = (f32x4){0.f, 0.f, 0.f, 0.f};
    float m = -1e30f, lsum = 0.f;

    if (sp < nt) STAGE(sp, 0);
    __syncthreads();                              // drains vmcnt before barrier

    int buf = 0;
    for (int st = sp; st < nt; st += nsp) {
        if (st + nsp < nt) STAGE(st + nsp, buf ^ 1);

        const int s0 = st << 6;
        const int c0 = s0 + lg * 8;               // cols of p[0..8)
        const int c1 = s0 + 32 + lg * 8;          // cols of p[8..16)

        float p[16];
        if (st != qb) {                           // interior: provably unmasked
            #pragma unroll
            for (int jj = 0; jj < 8; ++jj) {
                float4 k4 = lk[buf][lg * 8 + jj];      // 16-lane LDS broadcast
                p[jj] = fmaf(q4.x, k4.x, fmaf(q4.y, k4.y, fmaf(q4.z, k4.z, q4.w * k4.w)));
            }
            #pragma unroll
            for (int jj = 0; jj < 8; ++jj) {
                float4 k4 = lk[buf][32 + lg * 8 + jj];
                p[8 + jj] = fmaf(q4.x, k4.x, fmaf(q4.y, k4.y, fmaf(q4.z, k4.z, q4.w * k4.w)));
            }
        } else {                                  // edge tile: pre-exp mask only
            #pragma unroll
            for (int jj = 0; jj < 8; ++jj) {
                float4 k4 = lk[buf][lg * 8 + jj];
                float sc = fmaf(q4.x, k4.x, fmaf(q4.y, k4.y, fmaf(q4.z, k4.z, q4.w * k4.w)));
                p[jj] = (c0 + jj > qrow) ? -1e30f : sc;
            }
            #pragma unroll
            for (int jj = 0; jj < 8; ++jj) {
                float4 k4 = lk[buf][32 + lg * 8 + jj];
                float sc = fmaf(q4.x, k4.x, fmaf(q4.y, k4.y, fmaf(q4.z, k4.z, q4.w * k4.w)));
                p[8 + jj] = (c1 + jj > qrow) ? -1e30f : sc;
            }
        }

        // max tree (max3-friendly triples)
        float ma = fmaxf(fmaxf(p[0], p[1]), p[2]);
        float mb = fmaxf(fmaxf(p[3], p[4]), p[5]);
        float mc = fmaxf(fmaxf(p[6], p[7]), p[8]);
        float md = fmaxf(fmaxf(p[9], p[10]), p[11]);
        float me = fmaxf(fmaxf(p[12], p[13]), p[14]);
        float mt = fmaxf(fmaxf(fmaxf(ma, mb), fmaxf(mc, md)), fmaxf(me, p[15]));
        mt = fmaxf(mt, __shfl_xor(mt, 16));
        mt = fmaxf(mt, __shfl_xor(mt, 32));
        if (__any(mt > m + 8.f)) {                // deferred rescale (log2 units)
            float mnew = fmaxf(m, mt);
            float corr = exp2_fast(m - mnew);
            m = mnew;
            lsum *= corr;
            float cc0 = __shfl(corr, 4 * lg + 0); // lane 4*lg+r has lh == frag row lg*4+r
            float cc1 = __shfl(corr, 4 * lg + 1);
            float cc2 = __shfl(corr, 4 * lg + 2);
            float cc3 = __shfl(corr, 4 * lg + 3);
            #pragma unroll
            for (int n = 0; n < 8; ++n) {
                acc[n][0] *= cc0; acc[n][1] *= cc1; acc[n][2] *= cc2; acc[n][3] *= cc3;
            }
        }
        #pragma unroll
        for (int jj = 0; jj < 16; ++jj)
            p[jj] = exp2_fast(p[jj] - m);         // masked cols -> exp2(-1e30) == 0
        // sum tree (add3-friendly triples)
        float sa = (p[0] + p[1] + p[2]) + (p[3] + p[4] + p[5]);
        float sb = (p[6] + p[7] + p[8]) + (p[9] + p[10] + p[11]);
        float ps = sa + sb + ((p[12] + p[13] + p[14]) + p[15]);
        ps += __shfl_xor(ps, 16);
        ps += __shfl_xor(ps, 32);
        lsum += ps;

        // pack 16 fp32 -> 2x bf16x8 : RNE-adjust + v_perm pair-pack
        u32x4 w0, w1;
        #pragma unroll
        for (int i = 0; i < 4; ++i) {
            w0[i] = __builtin_amdgcn_perm(rne_u32(p[2 * i + 1]), rne_u32(p[2 * i]), 0x07060302u);
            w1[i] = __builtin_amdgcn_perm(rne_u32(p[8 + 2 * i + 1]), rne_u32(p[8 + 2 * i]), 0x07060302u);
        }
        bf16x8 pa0 = __builtin_bit_cast(bf16x8, w0);
        bf16x8 pa1 = __builtin_bit_cast(bf16x8, w1);

        #pragma unroll
        for (int n = 0; n < 8; ++n) {
            bf16x8 vf = *reinterpret_cast<const bf16x8*>(&lv[buf][(size_t)(n * 64 + lg * 16 + lh) * 8]);
            acc[n] = __builtin_amdgcn_mfma_f32_16x16x32_bf16(pa0, vf, acc[n], 0, 0, 0);
        }
        #pragma unroll
        for (int n = 0; n < 8; ++n) {
            bf16x8 vf = *reinterpret_cast<const bf16x8*>(&lv[buf][(size_t)(512 + n * 64 + lg * 16 + lh) * 8]);
            acc[n] = __builtin_amdgcn_mfma_f32_16x16x32_bf16(pa1, vf, acc[n], 0, 0, 0);
        }

        __syncthreads();                          // buf released; buf^1 staged & drained
        buf ^= 1;
    }
#undef STAGE

    unsigned short* mp = mpart + (size_t)(sp * 16 + bh) * T_ * HD_;
    #pragma unroll
    for (int n = 0; n < 8; ++n) {
        #pragma unroll
        for (int r = 0; r < 4; ++r) {
            int row = q0 + 16 * lg + 4 * r + w;   // D-frag row = lg*4+r -> q-row
            mp[(size_t)row * HD_ + n * 16 + lh] = f2bf(acc[n][r]);
        }
    }
    if (lg == 0)
        mlbuf[(size_t)(sp * 16 + bh) * T_ + qrow] = make_float2(m, lsum);
}

// ---------------- combine nsp s-split partials -> attnbf (bf16), online ------
__global__ __launch_bounds__(256) void k_combine(const unsigned short* __restrict__ mpart,
                                                 const float2* __restrict__ mlbuf,
                                                 unsigned short* __restrict__ attnbf,
                                                 int nsp) {
    int idx = blockIdx.x * 256 + threadIdx.x;   // [16][2048][32 d-quads]
    int bh = idx >> 16;
    int rem = idx & 65535;
    int t = rem >> 5, d0 = (rem & 31) * 4;
    float mg = -1e30f, den = 0.f;
    float ax = 0.f, ay = 0.f, az = 0.f, aw = 0.f;
    for (int s = 0; s < nsp; ++s) {
        float2 ml = mlbuf[(size_t)(s * 16 + bh) * T_ + t];
        ushort4 a = *reinterpret_cast<const ushort4*>(
            mpart + ((size_t)(s * 16 + bh) * T_ + t) * HD_ + d0);
        float mn = fmaxf(mg, ml.x);
        float cOld = exp2_fast(mg - mn);
        float cNew = exp2_fast(ml.x - mn);
        den = den * cOld + ml.y * cNew;
        ax = ax * cOld + bf2f(a.x) * cNew;
        ay = ay * cOld + bf2f(a.y) * cNew;
        az = az * cOld + bf2f(a.z) * cNew;
        aw = aw * cOld + bf2f(a.w) * cNew;
        mg = mn;
    }
    float inv = 1.f / den;
    int b = bh >> 3, h = bh & 7;
    ushort4 o;
    o.x = f2bf(ax * inv); o.y = f2bf(ay * inv);
    o.z = f2bf(az * inv); o.w = f2bf(aw * inv);
    *reinterpret_cast<ushort4*>(attnbf + ((size_t)(b * T_ + t) * C_ + h * HD_ + d0)) = o;
}

extern "C" void kernel_launch(void* const* d_in, const int* in_sizes, int n_in,
                              void* d_out, int out_size, void* d_ws, size_t ws_size,
                              hipStream_t stream) {
    const float* x     = (const float*)d_in[0];
    const float* Wq    = (const float*)d_in[1];
    const float* Wk    = (const float*)d_in[2];
    const float* Wv    = (const float*)d_in[3];
    const float* Wo    = (const float*)d_in[4];
    const float* scale = (const float*)d_in[5];
    float* out = (float*)d_out;

    // nsp=4 layout needs 46,137,344 B; fall back to nsp=2 (28,835,840 B)
    // if d_ws is smaller. Deterministic per process.
    const int nsp    = (ws_size >= 46137344) ? 4 : 2;
    const int lg2nsp = (nsp == 4) ? 2 : 1;

    char* ws = (char*)d_ws;
    // Lifetime-based layout (offsets scale with nsp):
    //   [0, nsp*8M)  mpart (attn->combine)  ALIASES: xbf [0,8M), wvbf [8M,10M)
    //   then qt (512K), kt (512K), vt (8M, ALIAS attnbf), wobf (2M), mlbuf (nsp*256K)
    size_t o = (size_t)nsp * 8388608;
    unsigned short* mpart  = (unsigned short*)(ws);
    unsigned short* xbf    = (unsigned short*)(ws);
    unsigned short* wvbf   = (unsigned short*)(ws + 8388608);
    float*          qt     = (float*)(ws + o);
    float*          kt     = (float*)(ws + o + 524288);
    unsigned short* vt     = (unsigned short*)(ws + o + 1048576);
    unsigned short* attnbf = (unsigned short*)(ws + o + 1048576);
    unsigned short* wobf   = (unsigned short*)(ws + o + 9437184);
    float2*         mlbuf  = (float2*)(ws + o + 11534336);

    k_convert_w<<<2048, 256, 0, stream>>>(Wv, Wo, wvbf, wobf);

    k_proj_qk<<<M_ / 16, 256, 0, stream>>>(x, Wq, Wk, scale, qt, kt, xbf);

    k_gemm128x64<2><<<(M_ / 128) * (C_ / 64), 256, 0, stream>>>(xbf, wvbf, (void*)vt, M_, C_, C_);

    k_attn64<<<32 * nsp * 16, 256, 0, stream>>>(
        reinterpret_cast<const float4*>(qt), reinterpret_cast<const float4*>(kt), vt,
        mpart, mlbuf, nsp, lg2nsp);

    k_combine<<<4096, 256, 0, stream>>>(mpart, mlbuf, attnbf, nsp);

    k_gemm128x64<0><<<(M_ / 128) * (C_ / 64), 256, 0, stream>>>(attnbf, wobf, (void*)out, M_, C_, C_);
}

// Round 17
// 123.615 us; speedup vs baseline: 1.1212x; 1.0459x over previous
//
#include <hip/hip_runtime.h>
#include <hip/hip_bf16.h>

#define B_  2
#define T_  2048
#define C_  1024
#define H_  8
#define HD_ 128
#define M_  (B_*T_)   // 4096

typedef short  bf16x8 __attribute__((ext_vector_type(8)));
typedef float  f32x4  __attribute__((ext_vector_type(4)));
typedef unsigned short u16x8 __attribute__((ext_vector_type(8)));
typedef unsigned int   u32x4 __attribute__((ext_vector_type(4)));

typedef const __attribute__((address_space(1))) void* gas_ptr;
typedef __attribute__((address_space(3))) void*       las_ptr;

#define L2E_ 1.4426950408889634f

static __device__ __forceinline__ unsigned short f2bf(float f) {
    unsigned int u = __float_as_uint(f);
    u += 0x7fffu + ((u >> 16) & 1u);   // round-to-nearest-even
    return (unsigned short)(u >> 16);
}
static __device__ __forceinline__ unsigned int rne_u32(float f) {
    unsigned int u = __float_as_uint(f);
    return u + 0x7fffu + ((u >> 16) & 1u);   // RNE-adjusted; bf16 = bytes 2,3
}
static __device__ __forceinline__ float bf2f(unsigned short u) {
    return __uint_as_float(((unsigned int)u) << 16);
}
static __device__ __forceinline__ float exp2_fast(float x) {
#if __has_builtin(__builtin_amdgcn_exp2f)
    return __builtin_amdgcn_exp2f(x);
#else
    return exp2f(x);
#endif
}

// ---------------- q/k tiny projection + fused x->bf16 + fused W converts -----
// Blocks [0,256): proj rows. Blocks [256,2304): Wv/Wo fp32->bf16 conversion.
// qt = log2e * [q3*scale, q3.dir]; kt = [k3, k3.dir]   layout [b*H+h][T] float4
__global__ __launch_bounds__(256) void k_proj_qk(const float* __restrict__ x,
                                                 const float* __restrict__ Wq,
                                                 const float* __restrict__ Wk,
                                                 const float* __restrict__ Wv,
                                                 const float* __restrict__ Wo,
                                                 const float* __restrict__ scale_p,
                                                 float* __restrict__ qt,
                                                 float* __restrict__ kt,
                                                 unsigned short* __restrict__ xbf,
                                                 unsigned short* __restrict__ wvbf,
                                                 unsigned short* __restrict__ wobf) {
    __shared__ __align__(16) float wl[48][260];
    __shared__ __align__(16) float xl[16][260];
    __shared__ float res[16][48];
    const int tid  = threadIdx.x;

    if (blockIdx.x >= (M_ / 16)) {               // converter blocks (uniform)
        int i = (blockIdx.x - M_ / 16) * 256 + tid;   // 0..524287 float4s
        const float* src; unsigned short* dst; int off;
        if (i < 262144) { src = Wv; dst = wvbf; off = i; }
        else            { src = Wo; dst = wobf; off = i - 262144; }
        float4 v = reinterpret_cast<const float4*>(src)[off];
        ushort4 o;
        o.x = f2bf(v.x); o.y = f2bf(v.y); o.z = f2bf(v.z); o.w = f2bf(v.w);
        reinterpret_cast<ushort4*>(dst)[off] = o;
        return;
    }

    const int row0 = blockIdx.x << 4;
    const int r    = tid >> 4, sub = tid & 15;
    float a0 = 0.f, a1 = 0.f, a2 = 0.f;

    for (int ch = 0; ch < 4; ++ch) {
        const int k0 = ch * 256;
        #pragma unroll
        for (int i = 0; i < 12; ++i) {
            int fi = i * 256 + tid;            // 0..3071
            int wr = fi >> 6, wc = (fi & 63) * 4;
            const float* src = (wr < 24) ? (Wq + (size_t)wr * C_) : (Wk + (size_t)(wr - 24) * C_);
            *reinterpret_cast<float4*>(&wl[wr][wc]) = *reinterpret_cast<const float4*>(src + k0 + wc);
        }
        #pragma unroll
        for (int i = 0; i < 4; ++i) {
            int fi = i * 256 + tid;            // 0..1023
            int xr = fi >> 6, xc = (fi & 63) * 4;
            size_t goff = (size_t)(row0 + xr) * C_ + k0 + xc;
            float4 xv = *reinterpret_cast<const float4*>(x + goff);
            *reinterpret_cast<float4*>(&xl[xr][xc]) = xv;
            ushort4 o;
            o.x = f2bf(xv.x); o.y = f2bf(xv.y); o.z = f2bf(xv.z); o.w = f2bf(xv.w);
            *reinterpret_cast<ushort4*>(xbf + goff) = o;   // fused x conversion
        }
        __syncthreads();
        const int oc = sub * 3;
        #pragma unroll 4
        for (int k = 0; k < 256; k += 4) {
            float4 xv = *reinterpret_cast<const float4*>(&xl[r][k]);
            float4 w0 = *reinterpret_cast<const float4*>(&wl[oc + 0][k]);
            float4 w1 = *reinterpret_cast<const float4*>(&wl[oc + 1][k]);
            float4 w2 = *reinterpret_cast<const float4*>(&wl[oc + 2][k]);
            a0 += xv.x * w0.x + xv.y * w0.y + xv.z * w0.z + xv.w * w0.w;
            a1 += xv.x * w1.x + xv.y * w1.y + xv.z * w1.z + xv.w * w1.w;
            a2 += xv.x * w2.x + xv.y * w2.y + xv.z * w2.z + xv.w * w2.w;
        }
        __syncthreads();
    }
    res[r][sub * 3 + 0] = a0;
    res[r][sub * 3 + 1] = a1;
    res[r][sub * 3 + 2] = a2;
    __syncthreads();

    {   // 16 rows x 16 (isK,h) = 256 threads
        const int rr = tid >> 4, s2 = tid & 15;
        const int isK = s2 >> 3, h = s2 & 7;
        const float r3 = 0.57735026918962576f;
        float d0 = (h & 4) ? r3 : -r3;
        float d1 = (h & 2) ? r3 : -r3;
        float d2 = (h & 1) ? r3 : -r3;
        const float* v3 = &res[rr][isK * 24 + h * 3];
        float a = v3[0], b = v3[1], c = v3[2];
        float ond = a * d0 + b * d1 + c * d2;
        float sc = scale_p[0];
        float4 ov = isK ? make_float4(a, b, c, ond)
                        : make_float4(a * sc * L2E_, b * sc * L2E_, c * sc * L2E_, ond * L2E_);
        float* dst = isK ? kt : qt;
        int grow = row0 + rr;
        int b_ = grow >> 11, t_idx = grow & (T_ - 1);
        reinterpret_cast<float4*>(dst)[(size_t)(b_ * H_ + h) * T_ + t_idx] = ov;
    }
}

// ---------------- bf16 MFMA GEMM, 128x64 tile, BK=64 (single-buffer) ---------
// Bijective XCD swizzle (nwg % 8 == 0): each XCD gets a CONTIGUOUS run of
// nwg/8 blocks -> 4 A-panels (1MB) + full B (2MB) fit its 4MB L2 (T1/m204).
// MODE 0: fp32 out [M][N].  MODE 2: bf16 out transposed into vt[(b*C+col)][t].
template <int MODE>
__global__ __launch_bounds__(256) void k_gemm128x64(const unsigned short* __restrict__ A,
                                                    const unsigned short* __restrict__ Bw,
                                                    void* __restrict__ Cout,
                                                    int Mdim, int Ndim, int Kdim) {
    __shared__ __align__(16) unsigned short lds_a[8][128][8];  // [kq][row][8]  16KB
    __shared__ __align__(16) unsigned short lds_b[8][64][8];   //               8KB
    const int tid = threadIdx.x;
    const int nbn = Ndim >> 6;
    const int cpx = (int)gridDim.x >> 3;                 // blocks per XCD
    const int bidx = (blockIdx.x & 7) * cpx + (blockIdx.x >> 3);
    const int bm = (bidx / nbn) << 7;
    const int bn = (bidx % nbn) << 6;
    const int w = tid >> 6, l = tid & 63;
    const int wm = (w >> 1) << 6, wn = (w & 1) << 5;
    const int lh = l & 15, lq = l >> 4;

    f32x4 acc[4][2];
    #pragma unroll
    for (int i = 0; i < 4; ++i)
        #pragma unroll
        for (int j = 0; j < 2; ++j)
            acc[i][j] = (f32x4){0.f, 0.f, 0.f, 0.f};

    for (int k0 = 0; k0 < Kdim; k0 += 64) {
        #pragma unroll
        for (int p = 0; p < 4; ++p) {
            int flat = p * 256 + tid;          // 0..1023 ; kq = flat>>7, row = flat&127
            int kq = flat >> 7, row = flat & 127;
            __builtin_amdgcn_global_load_lds((gas_ptr)(A + (size_t)(bm + row) * Kdim + k0 + kq * 8),
                (las_ptr)(&lds_a[0][0][0] + (size_t)flat * 8), 16, 0, 0);
        }
        #pragma unroll
        for (int p = 0; p < 2; ++p) {
            int flat = p * 256 + tid;          // 0..511 ; kq = flat>>6, row = flat&63
            int kq = flat >> 6, row = flat & 63;
            __builtin_amdgcn_global_load_lds((gas_ptr)(Bw + (size_t)(bn + row) * Kdim + k0 + kq * 8),
                (las_ptr)(&lds_b[0][0][0] + (size_t)flat * 8), 16, 0, 0);
        }
        __syncthreads();

        #pragma unroll
        for (int kk = 0; kk < 2; ++kk) {
            bf16x8 af[4], bfr[2];
            #pragma unroll
            for (int f = 0; f < 4; ++f)
                af[f] = *reinterpret_cast<const bf16x8*>(&lds_a[lq + 4 * kk][wm + f * 16 + lh][0]);
            #pragma unroll
            for (int f = 0; f < 2; ++f)
                bfr[f] = *reinterpret_cast<const bf16x8*>(&lds_b[lq + 4 * kk][wn + f * 16 + lh][0]);
            #pragma unroll
            for (int i = 0; i < 4; ++i)
                #pragma unroll
                for (int j = 0; j < 2; ++j)
                    acc[i][j] = __builtin_amdgcn_mfma_f32_16x16x32_bf16(af[i], bfr[j], acc[i][j], 0, 0, 0);
        }
        __syncthreads();
    }

    if constexpr (MODE == 0) {
        float* Cf = (float*)Cout;
        #pragma unroll
        for (int i = 0; i < 4; ++i) {
            int rbase = bm + wm + i * 16 + lq * 4;
            #pragma unroll
            for (int j = 0; j < 2; ++j) {
                int cidx = bn + wn + j * 16 + lh;
                #pragma unroll
                for (int r = 0; r < 4; ++r)
                    Cf[(size_t)(rbase + r) * Ndim + cidx] = acc[i][j][r];
            }
        }
    } else {
        __shared__ unsigned short ldsT[128][72];
        #pragma unroll
        for (int i = 0; i < 4; ++i)
            #pragma unroll
            for (int j = 0; j < 2; ++j)
                #pragma unroll
                for (int r = 0; r < 4; ++r)
                    ldsT[wm + i * 16 + lq * 4 + r][wn + j * 16 + lh] = f2bf(acc[i][j][r]);
        __syncthreads();
        unsigned short* vt_out = (unsigned short*)Cout;
        int c = tid & 63, part = tid >> 6;
        int b = bm >> 11, t0 = bm & (T_ - 1);
        unsigned short* dst = vt_out + ((size_t)b * C_ + bn + c) * T_ + t0 + part * 32;
        #pragma unroll
        for (int jj = 0; jj < 4; ++jj) {
            u16x8 v;
            #pragma unroll
            for (int k = 0; k < 8; ++k) v[k] = ldsT[part * 32 + jj * 8 + k][c];
            *reinterpret_cast<u16x8*>(dst + jj * 8) = v;
        }
    }
}

// ---------------- flash attention, KVBLK=64, s-split-nsp, LDS K+V, MFMA PV ---
// grid: 32 qb (heavy first, LPT) x nsp x 16 bh = 2048 blocks.
// Block = 64 q-rows (row = q0 + 4*lh + w), nt = qb+1 uniform 64-col tiles.
// Distance-2 prefetch with __syncthreads-only sync: STAGE(t+2nsp) is issued
// AFTER the barrier that releases buf (all waves done reading it); its loads
// are drained by the barrier one FULL iteration later -> max latency slack.
__global__ __launch_bounds__(256) void k_attn64(
        const float4* __restrict__ qt, const float4* __restrict__ kt,
        const unsigned short* __restrict__ vt,
        unsigned short* __restrict__ mpart,       // [nsp][16][2048][128] bf16 (unnormalized)
        float2* __restrict__ mlbuf,               // [nsp][16][2048] (m, lsum)
        int nsp, int lg2nsp) {
    __shared__ __align__(16) unsigned short lv[2][8192];   // 2 x 16KB V-tiles [128d][64s]
    __shared__ __align__(16) float4 lk[2][64];             // 2 x 1KB K-tiles
    const int tid = threadIdx.x;
    const int w = tid >> 6, l = tid & 63;
    const int lh = l & 15, lg = l >> 4;
    const int bid = blockIdx.x;
    const int qb = 31 - (bid >> (4 + lg2nsp));    // heavy q-blocks first (LPT)
    const int sp = (bid >> 4) & (nsp - 1);
    const int bh = bid & 15;
    const int q0 = qb << 6;
    const int qrow = q0 + 4 * lh + w;             // this lane's P-row (A-frag row)
    const int nt = qb + 1;                        // 64-col tiles, uniform per block

    const float4* qtb = qt + (size_t)bh * T_;
    const float4* ktb = kt + (size_t)bh * T_;
    const unsigned short* vtb = vt + (size_t)bh * HD_ * T_;

    // staging sources: flat slot f (16B) -> (kt2 = f>>9, n = (f>>6)&7,
    // lg2 = (f>>4)&3, lh2 = f&15); src = vtb[(n*16+lh2)*T + kt2*32 + lg2*8 + s0]
    const unsigned short* vsrc[4];
    #pragma unroll
    for (int i = 0; i < 4; ++i) {
        int f = i * 256 + tid;
        vsrc[i] = vtb + (size_t)((((f >> 6) & 7) * 16) + (f & 15)) * T_
                      + ((f >> 9) << 5) + ((f >> 4) & 3) * 8;
    }

#define STAGE(ST, BUF) do {                                                    \
    int s0_ = (ST) << 6;                                                       \
    __builtin_amdgcn_global_load_lds((gas_ptr)(vsrc[0] + s0_),                 \
        (las_ptr)(&lv[BUF][0] + (size_t)(0 * 256 + tid) * 8), 16, 0, 0);       \
    __builtin_amdgcn_global_load_lds((gas_ptr)(vsrc[1] + s0_),                 \
        (las_ptr)(&lv[BUF][0] + (size_t)(1 * 256 + tid) * 8), 16, 0, 0);       \
    __builtin_amdgcn_global_load_lds((gas_ptr)(vsrc[2] + s0_),                 \
        (las_ptr)(&lv[BUF][0] + (size_t)(2 * 256 + tid) * 8), 16, 0, 0);       \
    __builtin_amdgcn_global_load_lds((gas_ptr)(vsrc[3] + s0_),                 \
        (las_ptr)(&lv[BUF][0] + (size_t)(3 * 256 + tid) * 8), 16, 0, 0);       \
    __builtin_amdgcn_global_load_lds((gas_ptr)(ktb + s0_ + l),                 \
        (las_ptr)(&lk[BUF][0]), 16, 0, 0);                                     \
} while (0)

    const float4 q4 = qtb[qrow];
    f32x4 acc[8];
    #pragma unroll
    for (int n = 0; n < 8; ++n) acc[n] = (f32x4){0.f, 0.f, 0.f, 0.f};
    float m = -1e30f, lsum = 0.f;

    if (sp < nt)       STAGE(sp, 0);              // block-uniform guards
    if (sp + nsp < nt) STAGE(sp + nsp, 1);
    __syncthreads();                              // drains all prologue loads

    int buf = 0;
    for (int st = sp; st < nt; st += nsp) {
        const int s0 = st << 6;
        const int c0 = s0 + lg * 8;               // cols of p[0..8)
        const int c1 = s0 + 32 + lg * 8;          // cols of p[8..16)

        float p[16];
        if (st != qb) {                           // interior: provably unmasked
            #pragma unroll
            for (int jj = 0; jj < 8; ++jj) {
                float4 k4 = lk[buf][lg * 8 + jj];      // 16-lane LDS broadcast
                p[jj] = fmaf(q4.x, k4.x, fmaf(q4.y, k4.y, fmaf(q4.z, k4.z, q4.w * k4.w)));
            }
            #pragma unroll
            for (int jj = 0; jj < 8; ++jj) {
                float4 k4 = lk[buf][32 + lg * 8 + jj];
                p[8 + jj] = fmaf(q4.x, k4.x, fmaf(q4.y, k4.y, fmaf(q4.z, k4.z, q4.w * k4.w)));
            }
        } else {                                  // edge tile: pre-exp mask only
            #pragma unroll
            for (int jj = 0; jj < 8; ++jj) {
                float4 k4 = lk[buf][lg * 8 + jj];
                float sc = fmaf(q4.x, k4.x, fmaf(q4.y, k4.y, fmaf(q4.z, k4.z, q4.w * k4.w)));
                p[jj] = (c0 + jj > qrow) ? -1e30f : sc;
            }
            #pragma unroll
            for (int jj = 0; jj < 8; ++jj) {
                float4 k4 = lk[buf][32 + lg * 8 + jj];
                float sc = fmaf(q4.x, k4.x, fmaf(q4.y, k4.y, fmaf(q4.z, k4.z, q4.w * k4.w)));
                p[8 + jj] = (c1 + jj > qrow) ? -1e30f : sc;
            }
        }

        // max tree (max3-friendly triples)
        float ma = fmaxf(fmaxf(p[0], p[1]), p[2]);
        float mb = fmaxf(fmaxf(p[3], p[4]), p[5]);
        float mc = fmaxf(fmaxf(p[6], p[7]), p[8]);
        float md = fmaxf(fmaxf(p[9], p[10]), p[11]);
        float me = fmaxf(fmaxf(p[12], p[13]), p[14]);
        float mt = fmaxf(fmaxf(fmaxf(ma, mb), fmaxf(mc, md)), fmaxf(me, p[15]));
        mt = fmaxf(mt, __shfl_xor(mt, 16));
        mt = fmaxf(mt, __shfl_xor(mt, 32));
        if (__any(mt > m + 8.f)) {                // deferred rescale (log2 units)
            float mnew = fmaxf(m, mt);
            float corr = exp2_fast(m - mnew);
            m = mnew;
            lsum *= corr;
            float cc0 = __shfl(corr, 4 * lg + 0); // lane 4*lg+r has lh == frag row lg*4+r
            float cc1 = __shfl(corr, 4 * lg + 1);
            float cc2 = __shfl(corr, 4 * lg + 2);
            float cc3 = __shfl(corr, 4 * lg + 3);
            #pragma unroll
            for (int n = 0; n < 8; ++n) {
                acc[n][0] *= cc0; acc[n][1] *= cc1; acc[n][2] *= cc2; acc[n][3] *= cc3;
            }
        }
        #pragma unroll
        for (int jj = 0; jj < 16; ++jj)
            p[jj] = exp2_fast(p[jj] - m);         // masked cols -> exp2(-1e30) == 0
        // sum tree (add3-friendly triples)
        float sa = (p[0] + p[1] + p[2]) + (p[3] + p[4] + p[5]);
        float sb = (p[6] + p[7] + p[8]) + (p[9] + p[10] + p[11]);
        float ps = sa + sb + ((p[12] + p[13] + p[14]) + p[15]);
        ps += __shfl_xor(ps, 16);
        ps += __shfl_xor(ps, 32);
        lsum += ps;

        // pack 16 fp32 -> 2x bf16x8 : RNE-adjust + v_perm pair-pack
        u32x4 w0, w1;
        #pragma unroll
        for (int i = 0; i < 4; ++i) {
            w0[i] = __builtin_amdgcn_perm(rne_u32(p[2 * i + 1]), rne_u32(p[2 * i]), 0x07060302u);
            w1[i] = __builtin_amdgcn_perm(rne_u32(p[8 + 2 * i + 1]), rne_u32(p[8 + 2 * i]), 0x07060302u);
        }
        bf16x8 pa0 = __builtin_bit_cast(bf16x8, w0);
        bf16x8 pa1 = __builtin_bit_cast(bf16x8, w1);

        #pragma unroll
        for (int n = 0; n < 8; ++n) {
            bf16x8 vf = *reinterpret_cast<const bf16x8*>(&lv[buf][(size_t)(n * 64 + lg * 16 + lh) * 8]);
            acc[n] = __builtin_amdgcn_mfma_f32_16x16x32_bf16(pa0, vf, acc[n], 0, 0, 0);
        }
        #pragma unroll
        for (int n = 0; n < 8; ++n) {
            bf16x8 vf = *reinterpret_cast<const bf16x8*>(&lv[buf][(size_t)(512 + n * 64 + lg * 16 + lh) * 8]);
            acc[n] = __builtin_amdgcn_mfma_f32_16x16x32_bf16(pa1, vf, acc[n], 0, 0, 0);
        }

        __syncthreads();                          // all waves done reading buf;
                                                  // drains loads issued LAST iter
        if (st + 2 * nsp < nt) STAGE(st + 2 * nsp, buf);   // overwrite freed buf
        buf ^= 1;
    }
#undef STAGE

    unsigned short* mp = mpart + (size_t)(sp * 16 + bh) * T_ * HD_;
    #pragma unroll
    for (int n = 0; n < 8; ++n) {
        #pragma unroll
        for (int r = 0; r < 4; ++r) {
            int row = q0 + 16 * lg + 4 * r + w;   // D-frag row = lg*4+r -> q-row
            mp[(size_t)row * HD_ + n * 16 + lh] = f2bf(acc[n][r]);
        }
    }
    if (lg == 0)
        mlbuf[(size_t)(sp * 16 + bh) * T_ + qrow] = make_float2(m, lsum);
}

// ---------------- combine nsp s-split partials -> attnbf (bf16), online ------
__global__ __launch_bounds__(256) void k_combine(const unsigned short* __restrict__ mpart,
                                                 const float2* __restrict__ mlbuf,
                                                 unsigned short* __restrict__ attnbf,
                                                 int nsp) {
    int idx = blockIdx.x * 256 + threadIdx.x;   // [16][2048][32 d-quads]
    int bh = idx >> 16;
    int rem = idx & 65535;
    int t = rem >> 5, d0 = (rem & 31) * 4;
    float mg = -1e30f, den = 0.f;
    float ax = 0.f, ay = 0.f, az = 0.f, aw = 0.f;
    for (int s = 0; s < nsp; ++s) {
        float2 ml = mlbuf[(size_t)(s * 16 + bh) * T_ + t];
        ushort4 a = *reinterpret_cast<const ushort4*>(
            mpart + ((size_t)(s * 16 + bh) * T_ + t) * HD_ + d0);
        float mn = fmaxf(mg, ml.x);
        float cOld = exp2_fast(mg - mn);
        float cNew = exp2_fast(ml.x - mn);
        den = den * cOld + ml.y * cNew;
        ax = ax * cOld + bf2f(a.x) * cNew;
        ay = ay * cOld + bf2f(a.y) * cNew;
        az = az * cOld + bf2f(a.z) * cNew;
        aw = aw * cOld + bf2f(a.w) * cNew;
        mg = mn;
    }
    float inv = 1.f / den;
    int b = bh >> 3, h = bh & 7;
    ushort4 o;
    o.x = f2bf(ax * inv); o.y = f2bf(ay * inv);
    o.z = f2bf(az * inv); o.w = f2bf(aw * inv);
    *reinterpret_cast<ushort4*>(attnbf + ((size_t)(b * T_ + t) * C_ + h * HD_ + d0)) = o;
}

extern "C" void kernel_launch(void* const* d_in, const int* in_sizes, int n_in,
                              void* d_out, int out_size, void* d_ws, size_t ws_size,
                              hipStream_t stream) {
    const float* x     = (const float*)d_in[0];
    const float* Wq    = (const float*)d_in[1];
    const float* Wk    = (const float*)d_in[2];
    const float* Wv    = (const float*)d_in[3];
    const float* Wo    = (const float*)d_in[4];
    const float* scale = (const float*)d_in[5];
    float* out = (float*)d_out;

    // nsp=4 layout needs 46,137,344 B; fall back to nsp=2 (28,835,840 B)
    // if d_ws is smaller. Deterministic per process.
    const int nsp    = (ws_size >= 46137344) ? 4 : 2;
    const int lg2nsp = (nsp == 4) ? 2 : 1;

    char* ws = (char*)d_ws;
    // Lifetime-based layout (offsets scale with nsp):
    //   [0, nsp*8M)  mpart (attn->combine)  ALIASES: xbf [0,8M), wvbf [8M,10M)
    //   then qt (512K), kt (512K), vt (8M, ALIAS attnbf), wobf (2M), mlbuf (nsp*256K)
    size_t o = (size_t)nsp * 8388608;
    unsigned short* mpart  = (unsigned short*)(ws);
    unsigned short* xbf    = (unsigned short*)(ws);
    unsigned short* wvbf   = (unsigned short*)(ws + 8388608);
    float*          qt     = (float*)(ws + o);
    float*          kt     = (float*)(ws + o + 524288);
    unsigned short* vt     = (unsigned short*)(ws + o + 1048576);
    unsigned short* attnbf = (unsigned short*)(ws + o + 1048576);
    unsigned short* wobf   = (unsigned short*)(ws + o + 9437184);
    float2*         mlbuf  = (float2*)(ws + o + 11534336);

    k_proj_qk<<<M_ / 16 + 2048, 256, 0, stream>>>(x, Wq, Wk, Wv, Wo, scale,
                                                  qt, kt, xbf, wvbf, wobf);

    k_gemm128x64<2><<<(M_ / 128) * (C_ / 64), 256, 0, stream>>>(xbf, wvbf, (void*)vt, M_, C_, C_);

    k_attn64<<<32 * nsp * 16, 256, 0, stream>>>(
        reinterpret_cast<const float4*>(qt), reinterpret_cast<const float4*>(kt), vt,
        mpart, mlbuf, nsp, lg2nsp);

    k_combine<<<4096, 256, 0, stream>>>(mpart, mlbuf, attnbf, nsp);

    k_gemm128x64<0><<<(M_ / 128) * (C_ / 64), 256, 0, stream>>>(attnbf, wobf, (void*)out, M_, C_, C_);
}